// Round 1
// baseline (1305.614 us; speedup 1.0000x reference)
//
#include <hip/hip_runtime.h>
#include <cmath>

// LabelSmoothing KL loss:
//   loss_row = const - a*(sum_v log p - logp_t) - b*logp_t,  0 if t==IGNORE(0)
//   out = sum_rows(loss_row) / norm
// a = s/V, b = 1-s+a, const = a*log(a)*(V-1) + b*log(b)  (computed on host, fp64)
//
// Memory-bound: 1.05 GB read once. One block per row, float4 strided loads,
// wave64 shuffle reduce -> LDS -> one atomicAdd per block.

__global__ __launch_bounds__(256) void ls_row_kernel(
    const float* __restrict__ p,
    const int*   __restrict__ tgt,
    const int*   __restrict__ normp,
    float*       __restrict__ out,
    float cterm, int V)
{
    const int row = blockIdx.x;
    const int tid = threadIdx.x;
    const int t   = tgt[row];
    if (t == 0) return;  // ignore_index: row contributes exactly 0

    const float*  prow = p + (size_t)row * (size_t)V;
    const float4* p4   = (const float4*)prow;
    const int     nv4  = V >> 2;  // V=32000 -> 8000, 16B-aligned (V%4==0)

    float s0 = 0.f, s1 = 0.f, s2 = 0.f, s3 = 0.f;
    for (int i = tid; i < nv4; i += 256) {
        float4 v = p4[i];
        s0 += __logf(v.x);
        s1 += __logf(v.y);
        s2 += __logf(v.z);
        s3 += __logf(v.w);
    }
    float s = (s0 + s1) + (s2 + s3);

    // wave64 butterfly reduce
    #pragma unroll
    for (int off = 32; off > 0; off >>= 1)
        s += __shfl_down(s, off, 64);

    __shared__ float wsum[4];
    const int wid  = tid >> 6;
    const int lane = tid & 63;
    if (lane == 0) wsum[wid] = s;
    __syncthreads();

    if (tid == 0) {
        float tot = (wsum[0] + wsum[1]) + (wsum[2] + wsum[3]);
        float lt  = __logf(prow[t]);

        const float a = 0.1f / (float)V;
        const float b = 1.0f - 0.1f + a;
        float loss = cterm - a * (tot - lt) - b * lt;

        // norm scalar: int32 expected; fall back to float bit-pattern if the
        // harness delivered it as f32 (8192 as int < 2^30; as f32 bits > 2^30)
        int   ni = normp[0];
        float nf = (ni > 0 && ni < (1 << 30)) ? (float)ni : __int_as_float(ni);

        atomicAdd(out, loss / nf);
    }
}

extern "C" void kernel_launch(void* const* d_in, const int* in_sizes, int n_in,
                              void* d_out, int out_size, void* d_ws, size_t ws_size,
                              hipStream_t stream) {
    const float* p     = (const float*)d_in[0];
    const int*   tgt   = (const int*)d_in[1];
    const int*   normp = (const int*)d_in[2];
    float*       out   = (float*)d_out;

    const int BL = in_sizes[1];                 // B*L = 8192 rows
    const int V  = in_sizes[0] / in_sizes[1];   // vocab = 32000

    // entropy-like constant in fp64 (matches reference's numpy-scalar math)
    const double a = 0.1 / (double)V;
    const double b = 1.0 - 0.1 + a;
    const float  cterm = (float)(a * log(a) * (double)(V - 1) + b * log(b));

    // d_out is poisoned 0xAA before every timed launch; zero it (capture-safe)
    hipMemsetAsync(d_out, 0, sizeof(float), stream);

    ls_row_kernel<<<BL, 256, 0, stream>>>(p, tgt, normp, out, cterm, V);
}

// Round 2
// 1283.830 us; speedup vs baseline: 1.0170x; 1.0170x over previous
//
#include <hip/hip_runtime.h>
#include <cmath>

// LabelSmoothing KL loss:
//   loss_row = const - a*(sum_v log p - logp_t) - b*logp_t,  0 if t==IGNORE(0)
//   out = sum_rows(loss_row) / norm
//
// HBM-bound streaming read of 1.049 GB (floor ~166us @ 6.3 TB/s).
// One block per row; compile-time trip count (V=32000 -> NV4=8000) +
// unroll-4 so the compiler batches 4 independent global_load_dwordx4
// per thread (4-deep MLP) instead of one latency-exposed load per iter.

template<int NV4>
__global__ __launch_bounds__(256) void ls_row_kernel(
    const float* __restrict__ p,
    const int*   __restrict__ tgt,
    const int*   __restrict__ normp,
    float*       __restrict__ out,
    float cterm, int V, int nv4_rt)
{
    const int row = blockIdx.x;
    const int tid = threadIdx.x;
    const int t   = tgt[row];
    if (t == 0) return;  // ignore_index: row contributes exactly 0

    const float*  prow = p + (size_t)row * (size_t)V;
    const float4* p4   = (const float4*)prow;
    const int     nv4  = (NV4 > 0) ? NV4 : nv4_rt;

    float s0 = 0.f, s1 = 0.f, s2 = 0.f, s3 = 0.f;
    #pragma unroll 4
    for (int i = tid; i < nv4; i += 256) {
        float4 v = p4[i];
        s0 += __logf(v.x);
        s1 += __logf(v.y);
        s2 += __logf(v.z);
        s3 += __logf(v.w);
    }
    float s = (s0 + s1) + (s2 + s3);

    // wave64 butterfly reduce
    #pragma unroll
    for (int off = 32; off > 0; off >>= 1)
        s += __shfl_down(s, off, 64);

    __shared__ float wsum[4];
    const int wid  = tid >> 6;
    const int lane = tid & 63;
    if (lane == 0) wsum[wid] = s;
    __syncthreads();

    if (tid == 0) {
        float tot = (wsum[0] + wsum[1]) + (wsum[2] + wsum[3]);
        float lt  = __logf(prow[t]);

        const float a = 0.1f / (float)V;
        const float b = 1.0f - 0.1f + a;
        float loss = cterm - a * (tot - lt) - b * lt;

        int   ni = normp[0];
        float nf = (ni > 0 && ni < (1 << 30)) ? (float)ni : __int_as_float(ni);

        atomicAdd(out, loss / nf);
    }
}

extern "C" void kernel_launch(void* const* d_in, const int* in_sizes, int n_in,
                              void* d_out, int out_size, void* d_ws, size_t ws_size,
                              hipStream_t stream) {
    const float* p     = (const float*)d_in[0];
    const int*   tgt   = (const int*)d_in[1];
    const int*   normp = (const int*)d_in[2];
    float*       out   = (float*)d_out;

    const int BL = in_sizes[1];                 // B*L = 8192 rows
    const int V  = in_sizes[0] / in_sizes[1];   // vocab = 32000

    const double a = 0.1 / (double)V;
    const double b = 1.0 - 0.1 + a;
    const float  cterm = (float)(a * log(a) * (double)(V - 1) + b * log(b));

    // d_out poisoned 0xAA before every timed launch; zero it (capture-safe)
    hipMemsetAsync(d_out, 0, sizeof(float), stream);

    if (V == 32000) {
        ls_row_kernel<8000><<<BL, 256, 0, stream>>>(p, tgt, normp, out, cterm, V, 0);
    } else {
        ls_row_kernel<0><<<BL, 256, 0, stream>>>(p, tgt, normp, out, cterm, V, V >> 2);
    }
}